// Round 1
// baseline (643.001 us; speedup 1.0000x reference)
//
#include <hip/hip_runtime.h>
#include <math.h>

// ---------------- kernels ----------------

__global__ __launch_bounds__(256) void k_init(float* __restrict__ deg,
                                              float* __restrict__ h1acc,
                                              float* __restrict__ h2acc, int N) {
    int i = blockIdx.x * 256 + threadIdx.x;
    if (i < N * 16) h1acc[i] = 0.f;
    if (i < N * 8)  h2acc[i] = 0.f;
    if (i < N)      deg[i]   = 1.0f;   // self-loop contributes 1 to every node's degree
}

__global__ __launch_bounds__(256) void k_deg(const int* __restrict__ dst,
                                             float* __restrict__ deg, int E) {
    int e = blockIdx.x * 256 + threadIdx.x;
    if (e < E) atomicAdd(&deg[dst[e]], 1.0f);
}

__global__ __launch_bounds__(256) void k_dinv(float* __restrict__ deg, int N) {
    int i = blockIdx.x * 256 + threadIdx.x;
    if (i < N) deg[i] = rsqrtf(deg[i]);   // deg >= 1 always (self-loops)
}

// hw1[N,16] = x[N,128] @ W1[128,16]; 16 rows per 256-thread block
__global__ __launch_bounds__(256) void k_gemm1(const float* __restrict__ x,
                                               const float* __restrict__ W1,
                                               float* __restrict__ hw1, int N) {
    __shared__ float sW[128 * 16];
    __shared__ float sX[16][128];
    int t = threadIdx.x;
    for (int k = t; k < 128 * 16; k += 256) sW[k] = W1[k];
    int row0 = blockIdx.x * 16;
    for (int k = t; k < 16 * 128; k += 256) {
        int r = k >> 7, c = k & 127;
        int gr = row0 + r;
        sX[r][c] = (gr < N) ? x[gr * 128 + c] : 0.f;
    }
    __syncthreads();
    int r = t >> 4, c = t & 15;
    float acc = 0.f;
#pragma unroll 16
    for (int k = 0; k < 128; ++k) acc += sX[r][k] * sW[k * 16 + c];
    int gr = row0 + r;
    if (gr < N) hw1[gr * 16 + c] = acc;
}

// edge-parallel normalized scatter-add, 16 features: 16 lanes per edge
__global__ __launch_bounds__(256) void k_agg16(const int* __restrict__ src,
                                               const int* __restrict__ dst,
                                               const float* __restrict__ dinv,
                                               const float* __restrict__ hw,
                                               float* __restrict__ acc, int E) {
    int t = blockIdx.x * 256 + threadIdx.x;
    int e = t >> 4, j = t & 15;
    if (e >= E) return;
    int s = src[e], d = dst[e];
    float nm = dinv[s] * dinv[d];
    atomicAdd(&acc[d * 16 + j], nm * hw[s * 16 + j]);
}

// 8-feature variant: 8 lanes per edge
__global__ __launch_bounds__(256) void k_agg8(const int* __restrict__ src,
                                              const int* __restrict__ dst,
                                              const float* __restrict__ dinv,
                                              const float* __restrict__ hw,
                                              float* __restrict__ acc, int E) {
    int t = blockIdx.x * 256 + threadIdx.x;
    int e = t >> 3, j = t & 7;
    if (e >= E) return;
    int s = src[e], d = dst[e];
    float nm = dinv[s] * dinv[d];
    atomicAdd(&acc[d * 8 + j], nm * hw[s * 8 + j]);
}

// h1 = h1acc + dinv^2*hw1 + b1 ; hw2 = h1 @ W2[16,8]   (one thread per node)
__global__ __launch_bounds__(256) void k_l2(const float* __restrict__ h1acc,
                                            const float* __restrict__ hw1,
                                            const float* __restrict__ dinv,
                                            const float* __restrict__ W2,
                                            const float* __restrict__ b1,
                                            float* __restrict__ hw2, int N) {
    __shared__ float sW[16 * 8];
    __shared__ float sb[16];
    int t = threadIdx.x;
    if (t < 128) sW[t] = W2[t];
    if (t < 16)  sb[t] = b1[t];
    __syncthreads();
    int i = blockIdx.x * 256 + t;
    if (i >= N) return;
    float di = dinv[i], d2 = di * di;
    float h[16];
    const float4* a4 = (const float4*)(h1acc + (size_t)i * 16);
    const float4* w4 = (const float4*)(hw1 + (size_t)i * 16);
#pragma unroll
    for (int q = 0; q < 4; ++q) {
        float4 a = a4[q], w = w4[q];
        h[q * 4 + 0] = a.x + d2 * w.x + sb[q * 4 + 0];
        h[q * 4 + 1] = a.y + d2 * w.y + sb[q * 4 + 1];
        h[q * 4 + 2] = a.z + d2 * w.z + sb[q * 4 + 2];
        h[q * 4 + 3] = a.w + d2 * w.w + sb[q * 4 + 3];
    }
    float o[8] = {0, 0, 0, 0, 0, 0, 0, 0};
#pragma unroll
    for (int k = 0; k < 16; ++k)
#pragma unroll
        for (int j = 0; j < 8; ++j) o[j] += h[k] * sW[k * 8 + j];
    float4* out4 = (float4*)(hw2 + (size_t)i * 8);
    out4[0] = make_float4(o[0], o[1], o[2], o[3]);
    out4[1] = make_float4(o[4], o[5], o[6], o[7]);
}

// h2 = h2acc + dinv^2*hw2 + b2 ; z = sigmoid(h2 @ Wl + bl)
__global__ __launch_bounds__(256) void k_z(const float* __restrict__ h2acc,
                                           const float* __restrict__ hw2,
                                           const float* __restrict__ dinv,
                                           const float* __restrict__ Wl,
                                           const float* __restrict__ b2,
                                           const float* __restrict__ bl,
                                           float* __restrict__ z, int N) {
    __shared__ float sW[8], sb[8], sbl;
    int t = threadIdx.x;
    if (t < 8) { sW[t] = Wl[t]; sb[t] = b2[t]; }
    if (t == 0) sbl = bl[0];
    __syncthreads();
    int i = blockIdx.x * 256 + t;
    if (i >= N) return;
    float di = dinv[i], d2 = di * di;
    float s = sbl;
    const float4* a4 = (const float4*)(h2acc + (size_t)i * 8);
    const float4* w4 = (const float4*)(hw2 + (size_t)i * 8);
#pragma unroll
    for (int q = 0; q < 2; ++q) {
        float4 a = a4[q], w = w4[q];
        s += (a.x + d2 * w.x + sb[q * 4 + 0]) * sW[q * 4 + 0];
        s += (a.y + d2 * w.y + sb[q * 4 + 1]) * sW[q * 4 + 1];
        s += (a.z + d2 * w.z + sb[q * 4 + 2]) * sW[q * 4 + 2];
        s += (a.w + d2 * w.w + sb[q * 4 + 3]) * sW[q * 4 + 3];
    }
    z[i] = 1.f / (1.f + __expf(-s));
}

__global__ __launch_bounds__(256) void k_pred(const int* __restrict__ pe,
                                              const float* __restrict__ z,
                                              float* __restrict__ out, int P) {
    int p = blockIdx.x * 256 + threadIdx.x;
    if (p < P) out[p] = z[pe[2 * p]] * z[pe[2 * p + 1]];
}

// ---------------- launch ----------------

extern "C" void kernel_launch(void* const* d_in, const int* in_sizes, int n_in,
                              void* d_out, int out_size, void* d_ws, size_t ws_size,
                              hipStream_t stream) {
    const float* x  = (const float*)d_in[0];
    const int*   ei = (const int*)d_in[1];
    const int*   pe = (const int*)d_in[2];
    const float* W1 = (const float*)d_in[3];
    const float* b1 = (const float*)d_in[4];
    const float* W2 = (const float*)d_in[5];
    const float* b2 = (const float*)d_in[6];
    const float* Wl = (const float*)d_in[7];
    const float* bl = (const float*)d_in[8];
    float* out = (float*)d_out;

    const int N = in_sizes[0] / 128;
    const int E = in_sizes[1] / 2;
    const int P = in_sizes[2] / 2;

    const int* src = ei;
    const int* dst = ei + E;

    // workspace layout (floats); N*4 bytes is 16B-aligned (N=100000)
    float* ws    = (float*)d_ws;
    float* deg   = ws;            // [N]  -> becomes dinv in-place
    float* hw1   = ws + (size_t)N;        // [N,16]
    float* h1acc = ws + (size_t)17 * N;   // [N,16]
    float* hw2   = ws + (size_t)33 * N;   // [N,8]
    float* h2acc = ws + (size_t)41 * N;   // [N,8]
    float* z     = ws + (size_t)49 * N;   // [N]

    const int B = 256;

    // 1. init accumulators + deg=1 (self loops)
    k_init<<<(N * 16 + B - 1) / B, B, 0, stream>>>(deg, h1acc, h2acc, N);
    // 2. degree histogram
    k_deg<<<(E + B - 1) / B, B, 0, stream>>>(dst, deg, E);
    // 3. dinv
    k_dinv<<<(N + B - 1) / B, B, 0, stream>>>(deg, N);
    // 4. hw1 = x @ W1
    k_gemm1<<<(N + 15) / 16, B, 0, stream>>>(x, W1, hw1, N);
    // 5. aggregate layer 1 (edge-parallel atomics)
    {
        long long threads = (long long)E * 16;
        k_agg16<<<(int)((threads + B - 1) / B), B, 0, stream>>>(src, dst, deg, hw1, h1acc, E);
    }
    // 6. finalize layer 1 + GEMM2 -> hw2
    k_l2<<<(N + B - 1) / B, B, 0, stream>>>(h1acc, hw1, deg, W2, b1, hw2, N);
    // 7. aggregate layer 2
    {
        long long threads = (long long)E * 8;
        k_agg8<<<(int)((threads + B - 1) / B), B, 0, stream>>>(src, dst, deg, hw2, h2acc, E);
    }
    // 8. finalize layer 2 + sigmoid -> z
    k_z<<<(N + B - 1) / B, B, 0, stream>>>(h2acc, hw2, deg, Wl, b2, bl, z, N);
    // 9. link prediction
    k_pred<<<(P + B - 1) / B, B, 0, stream>>>(pe, z, out, P);
}